// Round 2
// baseline (459.981 us; speedup 1.0000x reference)
//
#include <hip/hip_runtime.h>

#define N_TOK 16384
#define HID   4096
#define N_EXP 64
#define TOPK  8

#define CH    64              // K per stage
#define NST   (HID / CH)      // 64 stages

// d_out layout (floats, concatenated in reference return order)
#define OFF_WT   (N_TOK * N_EXP)
#define OFF_IDX  (OFF_WT + N_TOK * TOPK)
#define OFF_MASK (OFF_IDX + N_TOK * TOPK)

typedef __attribute__((ext_vector_type(8))) _Float16 f16x8;
typedef __attribute__((ext_vector_type(4))) float f32x4;

// split f into f16 hi (RNE) + f16 lo (RNE of residual): hi+lo ~ f with rel err 2^-24
static __device__ __forceinline__ void hsplit(float f, unsigned short &h, unsigned short &l)
{
    _Float16 hh = (_Float16)f;           // v_cvt_f16_f32 (RNE)
    float r = f - (float)hh;
    _Float16 hl = (_Float16)r;
    h = __builtin_bit_cast(unsigned short, hh);
    l = __builtin_bit_cast(unsigned short, hl);
}

// ---------------------------------------------------------------------------
// Kernel 0: split W (fp32 [64][4096]) into f16 hi/lo planes in workspace.
// ---------------------------------------------------------------------------
__global__ __launch_bounds__(256)
void prep_w(const float* __restrict__ W,
            unsigned short* __restrict__ wh, unsigned short* __restrict__ wl)
{
    const int i = blockIdx.x * 256 + threadIdx.x;     // 65536 float4s
    float4 f = ((const float4*)W)[i];
    unsigned short h0,l0,h1,l1,h2,l2,h3,l3;
    hsplit(f.x,h0,l0); hsplit(f.y,h1,l1); hsplit(f.z,h2,l2); hsplit(f.w,h3,l3);
    *(uint2*)&wh[4*i] = make_uint2((unsigned)h0 | ((unsigned)h1<<16), (unsigned)h2 | ((unsigned)h3<<16));
    *(uint2*)&wl[4*i] = make_uint2((unsigned)l0 | ((unsigned)l1<<16), (unsigned)l2 | ((unsigned)l3<<16));
}

// ---------------------------------------------------------------------------
// Kernel A: f16x3 (Ootomo-split) MFMA GEMM. router = x @ W^T + b, full K.
// Grid 256 blocks (64tok x 64exp tile each), 4 waves (2x2), tile 32x32/wave.
// LDS: XOR-swizzled (quad ^ row&7) 128B rows -> conflict-free ds_read_b128.
// Double-buffered reg-staged pipeline, one barrier per 64-K stage.
// x ~= xh + xl, w ~= wh + wl (f16 pairs); x.w ~= xh.wh + xh.wl + xl.wh
// (dropped xl.wl ~ 2^-24) -> logit error ~1e-7, below fp32 accum noise.
// ---------------------------------------------------------------------------
__global__ __launch_bounds__(256, 1)
void router_gemm(const float* __restrict__ x,
                 const unsigned short* __restrict__ wh,
                 const unsigned short* __restrict__ wl,
                 const float* __restrict__ b,
                 float* __restrict__ router)
{
    __shared__ unsigned short sXh[2][64 * CH];
    __shared__ unsigned short sXl[2][64 * CH];
    __shared__ unsigned short sWh[2][64 * CH];
    __shared__ unsigned short sWl[2][64 * CH];

    const int tid = threadIdx.x;
    const long t0 = (long)blockIdx.x * 64;

    // staging roles: x slab pos p = tid + 256*j (j<4): row=p>>4, float4 kq=p&15
    //                W slab pos p = tid + 256*j (j<2): row=p>>3, quad  q =p&7
    const int xr0 = tid >> 4, xkq = tid & 15;
    const int wr0 = tid >> 3, wq  = tid & 7;

    const float*          xb  = x  + (t0 + xr0) * (long)HID + xkq * 4;
    const unsigned short* whb = wh + (long)wr0 * HID + wq * 8;
    const unsigned short* wlb = wl + (long)wr0 * HID + wq * 8;

    // compute roles: 2x2 wave grid, each wave 32 tok x 32 exp (2x2 16x16 tiles)
    const int lane = tid & 63, wv = tid >> 6;
    const int wr = wv >> 1, wc = wv & 1;
    const int lrow = lane & 15, lg = lane >> 4, sw = lane & 7;

    float4 gx[4]; uint4 gwh[2], gwl[2];
    f32x4 acc[2][2] = {};

    auto LOAD = [&](int st) {
        const long o = (long)st * CH;
#pragma unroll
        for (int j = 0; j < 4; ++j)
            gx[j] = *(const float4*)(xb + (long)(16 * j) * HID + o);
#pragma unroll
        for (int j = 0; j < 2; ++j) {
            gwh[j] = *(const uint4*)(whb + (long)(32 * j) * HID + o);
            gwl[j] = *(const uint4*)(wlb + (long)(32 * j) * HID + o);
        }
    };

    auto STORE = [&](int buf) {
#pragma unroll
        for (int j = 0; j < 4; ++j) {
            const int r = xr0 + 16 * j;
            const int q = xkq >> 1;
            const int a = r * CH + (((q ^ (r & 7)) << 3) | ((xkq & 1) << 2));
            unsigned short h0,l0,h1,l1,h2,l2,h3,l3;
            hsplit(gx[j].x,h0,l0); hsplit(gx[j].y,h1,l1);
            hsplit(gx[j].z,h2,l2); hsplit(gx[j].w,h3,l3);
            *(uint2*)&sXh[buf][a] = make_uint2((unsigned)h0 | ((unsigned)h1<<16), (unsigned)h2 | ((unsigned)h3<<16));
            *(uint2*)&sXl[buf][a] = make_uint2((unsigned)l0 | ((unsigned)l1<<16), (unsigned)l2 | ((unsigned)l3<<16));
        }
#pragma unroll
        for (int j = 0; j < 2; ++j) {
            const int r = wr0 + 32 * j;
            const int a = r * CH + ((wq ^ (r & 7)) << 3);
            *(uint4*)&sWh[buf][a] = gwh[j];
            *(uint4*)&sWl[buf][a] = gwl[j];
        }
    };

    auto COMPUTE = [&](int buf) {
#pragma unroll
        for (int ks = 0; ks < CH / 32; ++ks) {
            f16x8 ah[2], al[2], bh[2], bl[2];
            const int qs = ((ks * 4 + lg) ^ sw) << 3;
#pragma unroll
            for (int ti = 0; ti < 2; ++ti) {
                const int a = (wr * 32 + ti * 16 + lrow) * CH + qs;
                ah[ti] = *(const f16x8*)&sXh[buf][a];
                al[ti] = *(const f16x8*)&sXl[buf][a];
            }
#pragma unroll
            for (int ei = 0; ei < 2; ++ei) {
                const int a = (wc * 32 + ei * 16 + lrow) * CH + qs;
                bh[ei] = *(const f16x8*)&sWh[buf][a];
                bl[ei] = *(const f16x8*)&sWl[buf][a];
            }
#pragma unroll
            for (int ti = 0; ti < 2; ++ti)
#pragma unroll
                for (int ei = 0; ei < 2; ++ei) {
                    acc[ti][ei] = __builtin_amdgcn_mfma_f32_16x16x32_f16(ah[ti], bh[ei], acc[ti][ei], 0, 0, 0);
                    acc[ti][ei] = __builtin_amdgcn_mfma_f32_16x16x32_f16(ah[ti], bl[ei], acc[ti][ei], 0, 0, 0);
                    acc[ti][ei] = __builtin_amdgcn_mfma_f32_16x16x32_f16(al[ti], bh[ei], acc[ti][ei], 0, 0, 0);
                }
        }
    };

    LOAD(0);
    STORE(0);
    __syncthreads();
#pragma unroll 1
    for (int st = 0; st < NST; ++st) {
        if (st + 1 < NST) LOAD(st + 1);       // HBM latency hides under compute
        COMPUTE(st & 1);
        if (st + 1 < NST) STORE((st + 1) & 1);
        __syncthreads();                       // one barrier per stage
    }

    // epilogue: direct store (no atomics), bias fused
#pragma unroll
    for (int ei = 0; ei < 2; ++ei) {
        const int e = wc * 32 + ei * 16 + lrow;
        const float bias = b[e];
#pragma unroll
        for (int ti = 0; ti < 2; ++ti)
#pragma unroll
            for (int r = 0; r < 4; ++r) {
                const long tok = t0 + wr * 32 + ti * 16 + lg * 4 + r;
                router[tok * N_EXP + e] = acc[ti][ei][r] + bias;
            }
    }
}

// ---------------------------------------------------------------------------
// Kernel B: softmax + top-8 (tie -> lowest index) + renorm weights + indices.
// Wave per token. Logits already include bias.
// ---------------------------------------------------------------------------
__global__ __launch_bounds__(256)
void router_topk(const float* __restrict__ router, float* __restrict__ out)
{
    const int tid  = threadIdx.x;
    const int lane = tid & 63;
    const int wv   = tid >> 6;
    const int n    = blockIdx.x * 4 + wv;

    float l = router[(long)n * N_EXP + lane];

    float m = l;
#pragma unroll
    for (int o = 32; o > 0; o >>= 1) m = fmaxf(m, __shfl_xor(m, o));
    float p = expf(l - m);
    float Z = p;
#pragma unroll
    for (int o = 32; o > 0; o >>= 1) Z += __shfl_xor(Z, o);
    float prob = p / Z;

    float cur = prob;
    float myv = 0.f;
    int   myi = 0;
    float ssum = 0.f;
#pragma unroll
    for (int k = 0; k < TOPK; ++k) {
        float v = cur;
        int   id = lane;
#pragma unroll
        for (int o = 32; o > 0; o >>= 1) {
            float ov = __shfl_xor(v, o);
            int   oi = __shfl_xor(id, o);
            if (ov > v || (ov == v && oi < id)) { v = ov; id = oi; }
        }
        if (lane == k)  { myv = v; myi = id; }
        if (lane == id) cur = -1.f;
        ssum += v;
    }

    if (lane < TOPK) {
        out[OFF_WT  + (long)n * TOPK + lane] = myv / ssum;
        out[OFF_IDX + (long)n * TOPK + lane] = (float)myi;
    }
}

// ---------------------------------------------------------------------------
// Kernel C: full coalesced one-hot mask write: mask[e][k][n] = (idx[n][k]==e).
// Replaces memset + scatter; every mask element written exactly once.
// ---------------------------------------------------------------------------
__global__ __launch_bounds__(256)
void mask_fill(const float* __restrict__ idxf, float* __restrict__ mask)
{
    const int bid = blockIdx.x;           // 2048 blocks
    const int ek  = bid >> 2, qtr = bid & 3;
    const int k   = ek & 7;
    const float fe = (float)(ek >> 3);
    float* mbase = mask + (long)ek * N_TOK;
#pragma unroll
    for (int j = 0; j < 4; ++j) {
        const int n = qtr * 4096 + j * 1024 + threadIdx.x * 4;
        float4 v;
        v.x = (idxf[(long)(n + 0) * TOPK + k] == fe) ? 1.f : 0.f;
        v.y = (idxf[(long)(n + 1) * TOPK + k] == fe) ? 1.f : 0.f;
        v.z = (idxf[(long)(n + 2) * TOPK + k] == fe) ? 1.f : 0.f;
        v.w = (idxf[(long)(n + 3) * TOPK + k] == fe) ? 1.f : 0.f;
        *(float4*)&mbase[n] = v;
    }
}

extern "C" void kernel_launch(void* const* d_in, const int* in_sizes, int n_in,
                              void* d_out, int out_size, void* d_ws, size_t ws_size,
                              hipStream_t stream)
{
    const float* x = (const float*)d_in[0];
    const float* W = (const float*)d_in[1];
    const float* b = (const float*)d_in[2];
    float* out = (float*)d_out;

    unsigned short* wsh = (unsigned short*)d_ws;              // W hi plane (512 KB)
    unsigned short* wsl = wsh + (size_t)N_EXP * HID;          // W lo plane (512 KB)

    // no memset: router fully written by GEMM, wt/idx by topk, mask by mask_fill
    hipLaunchKernelGGL(prep_w,      dim3(N_EXP * HID / 1024), dim3(256), 0, stream, W, wsh, wsl);
    hipLaunchKernelGGL(router_gemm, dim3(N_TOK / 64),         dim3(256), 0, stream, x, wsh, wsl, b, out);
    hipLaunchKernelGGL(router_topk, dim3(N_TOK / 4),          dim3(256), 0, stream, out, out);
    hipLaunchKernelGGL(mask_fill,   dim3(N_EXP * TOPK * 4),   dim3(256), 0, stream,
                       out + OFF_IDX, out + OFF_MASK);
}